// Round 1
// baseline (133.425 us; speedup 1.0000x reference)
//
#include <hip/hip_runtime.h>
#include <math.h>

// FrequencyAdaptiveNorm: multi-scale (w=5,10,20) centered sliding-window
// normalization over L, softmax-weighted sum of scales.
// x: (B=32, L=2048, F=256) f32, weights: (3,) f32, out: (32,2048,256) f32.
//
// Strategy: one thread per f-column per L-chunk; running window sums
// (sum, sumsq) per scale maintained across a sequential scan of the chunk.
// All global accesses coalesced across f (threadIdx.x == f).

#define B_ 32
#define L_ 2048
#define F_ 256
#define TL 64   // L-chunk per block

__device__ __forceinline__ float gval(const float* __restrict__ xb, int l, int f) {
    if ((unsigned)l >= (unsigned)L_) return 0.0f;
    float v = xb[l * F_ + f];
    // nan_to_num(nan=0, posinf=0, neginf=0)
    return isfinite(v) ? v : 0.0f;
}

__global__ __launch_bounds__(256)
void fan_kernel(const float* __restrict__ x,
                const float* __restrict__ w,
                float* __restrict__ out) {
    const int f  = threadIdx.x;          // 0..255 == F
    const int b  = blockIdx.y;
    const int l0 = blockIdx.x * TL;
    const float* xb = x   + (size_t)b * L_ * F_;
    float*       ob = out + (size_t)b * L_ * F_;

    // softmax over the 3 fusion logits (uniform across threads; cached)
    const float w0 = w[0], w1 = w[1], w2 = w[2];
    const float m  = fmaxf(w0, fmaxf(w1, w2));
    const float e0 = expf(w0 - m), e1 = expf(w1 - m), e2 = expf(w2 - m);
    const float inv = 1.0f / (e0 + e1 + e2);
    const float ws5 = e0 * inv, ws10 = e1 * inv, ws20 = e2 * inv;

    // init running sums for window position j = l0:
    //   w5: [j-2, j+2], w10: [j-5, j+4], w20: [j-10, j+9]
    float s5 = 0.f, q5 = 0.f, s10 = 0.f, q10 = 0.f, s20 = 0.f, q20 = 0.f;
#pragma unroll
    for (int d = -10; d <= 9; ++d) {
        const float v  = gval(xb, l0 + d, f);
        const float v2 = v * v;
        s20 += v; q20 += v2;
        if (d >= -5 && d <= 4) { s10 += v; q10 += v2; }
        if (d >= -2 && d <= 2) { s5  += v; q5  += v2; }
    }

    const float eps = 1e-5f;
#pragma unroll 4
    for (int t = 0; t < TL; ++t) {
        const int j = l0 + t;
        const float xc = gval(xb, j, f);
        float acc = 0.0f;
        // scale w=5, center=2: valid j in [2, L-3]
        if (j >= 2 && j <= L_ - 3) {
            const float mean = s5 * 0.2f;
            const float var  = fmaxf(q5 * 0.2f - mean * mean, 0.0f);
            acc += ws5 * (xc - mean) * rsqrtf(var + eps);
        }
        // scale w=10, center=5: valid j in [5, L-5]
        if (j >= 5 && j <= L_ - 5) {
            const float mean = s10 * 0.1f;
            const float var  = fmaxf(q10 * 0.1f - mean * mean, 0.0f);
            acc += ws10 * (xc - mean) * rsqrtf(var + eps);
        }
        // scale w=20, center=10: valid j in [10, L-10]
        if (j >= 10 && j <= L_ - 10) {
            const float mean = s20 * 0.05f;
            const float var  = fmaxf(q20 * 0.05f - mean * mean, 0.0f);
            acc += ws20 * (xc - mean) * rsqrtf(var + eps);
        }
        ob[j * F_ + f] = acc;

        // slide all windows j -> j+1
        const float a5  = gval(xb, j + 3,  f), r5  = gval(xb, j - 2,  f);
        s5  += a5  - r5;  q5  += a5 * a5   - r5 * r5;
        const float a10 = gval(xb, j + 5,  f), r10 = gval(xb, j - 5,  f);
        s10 += a10 - r10; q10 += a10 * a10 - r10 * r10;
        const float a20 = gval(xb, j + 10, f), r20 = gval(xb, j - 10, f);
        s20 += a20 - r20; q20 += a20 * a20 - r20 * r20;
    }
}

extern "C" void kernel_launch(void* const* d_in, const int* in_sizes, int n_in,
                              void* d_out, int out_size, void* d_ws, size_t ws_size,
                              hipStream_t stream) {
    const float* x = (const float*)d_in[0];
    const float* w = (const float*)d_in[1];
    float* out = (float*)d_out;
    (void)in_sizes; (void)n_in; (void)out_size; (void)d_ws; (void)ws_size;

    dim3 grid(L_ / TL, B_);   // (32, 32) = 1024 blocks
    dim3 block(F_);           // 256 threads, one per feature
    hipLaunchKernelGGL(fan_kernel, grid, block, 0, stream, x, w, out);
}

// Round 2
// 44.277 us; speedup vs baseline: 3.0134x; 3.0134x over previous
//
#include <hip/hip_runtime.h>
#include <math.h>

// FrequencyAdaptiveNorm: multi-scale (w=5,10,20) centered sliding-window
// normalization over L, softmax-weighted sum of scales.
// x: (B=32, L=2048, F=256) f32, weights: (3,) f32, out: (32,2048,256) f32.
//
// v2: register delay-line. Each thread owns one f-column for a TL=32 chunk
// of L. ring[21] holds x[j-10..j+10] in VGPRs; one global load per output
// element (x[j+11]); all window add/subtract operands come from the ring at
// static indices. Loads per element: 7 -> 1. Grid doubled for occupancy.

#define B_ 32
#define L_ 2048
#define F_ 256
#define TL 32   // L-chunk per block (grid = 64 x 32 = 2048 blocks)

__device__ __forceinline__ float gval(const float* __restrict__ xb, int l, int f) {
    if ((unsigned)l >= (unsigned)L_) return 0.0f;
    float v = xb[l * F_ + f];
    // nan_to_num(nan=0, posinf=0, neginf=0)
    return isfinite(v) ? v : 0.0f;
}

__global__ __launch_bounds__(256, 8)
void fan_kernel(const float* __restrict__ x,
                const float* __restrict__ w,
                float* __restrict__ out) {
    const int f  = threadIdx.x;          // 0..255 == F
    const int b  = blockIdx.y;
    const int l0 = blockIdx.x * TL;
    const float* xb = x   + (size_t)b * L_ * F_;
    float*       ob = out + (size_t)b * L_ * F_;

    // softmax over the 3 fusion logits (uniform across threads)
    const float w0 = w[0], w1 = w[1], w2 = w[2];
    const float m  = fmaxf(w0, fmaxf(w1, w2));
    const float e0 = expf(w0 - m), e1 = expf(w1 - m), e2 = expf(w2 - m);
    const float inv = 1.0f / (e0 + e1 + e2);
    const float ws5 = e0 * inv, ws10 = e1 * inv, ws20 = e2 * inv;

    // delay line: ring[d] = x[l0 - 10 + d], d = 0..20  (x[j-10..j+10] at j=l0)
    float ring[21];
#pragma unroll
    for (int d = 0; d < 21; ++d) ring[d] = gval(xb, l0 - 10 + d, f);

    // init running sums for output position j = l0:
    //   w5: [j-2,j+2] = ring[8..12], w10: [j-5,j+4] = ring[5..14],
    //   w20: [j-10,j+9] = ring[0..19]
    float s5 = 0.f, q5 = 0.f, s10 = 0.f, q10 = 0.f, s20 = 0.f, q20 = 0.f;
#pragma unroll
    for (int d = 0; d < 20; ++d) { s20 += ring[d]; q20 += ring[d] * ring[d]; }
#pragma unroll
    for (int d = 5; d < 15; ++d) { s10 += ring[d]; q10 += ring[d] * ring[d]; }
#pragma unroll
    for (int d = 8; d < 13; ++d) { s5  += ring[d]; q5  += ring[d] * ring[d]; }

    const float eps = 1e-5f;
#pragma unroll 4
    for (int t = 0; t < TL; ++t) {
        const int j = l0 + t;
        // independent prefetch for the ring tail (used next iteration)
        const float vnew = gval(xb, j + 11, f);

        const float xc = ring[10];
        float acc = 0.0f;
        // scale w=5, center=2: valid j in [2, L-3]
        if (j >= 2 && j <= L_ - 3) {
            const float mean = s5 * 0.2f;
            const float var  = fmaxf(q5 * 0.2f - mean * mean, 0.0f);
            acc += ws5 * (xc - mean) * rsqrtf(var + eps);
        }
        // scale w=10, center=5: valid j in [5, L-5]
        if (j >= 5 && j <= L_ - 5) {
            const float mean = s10 * 0.1f;
            const float var  = fmaxf(q10 * 0.1f - mean * mean, 0.0f);
            acc += ws10 * (xc - mean) * rsqrtf(var + eps);
        }
        // scale w=20, center=10: valid j in [10, L-10]
        if (j >= 10 && j <= L_ - 10) {
            const float mean = s20 * 0.05f;
            const float var  = fmaxf(q20 * 0.05f - mean * mean, 0.0f);
            acc += ws20 * (xc - mean) * rsqrtf(var + eps);
        }
        ob[j * F_ + f] = acc;

        // slide all windows j -> j+1 (all operands from the ring)
        const float a5  = ring[13], r5  = ring[8];
        s5  += a5  - r5;  q5  += a5 * a5   - r5 * r5;
        const float a10 = ring[15], r10 = ring[5];
        s10 += a10 - r10; q10 += a10 * a10 - r10 * r10;
        const float a20 = ring[20], r20 = ring[0];
        s20 += a20 - r20; q20 += a20 * a20 - r20 * r20;

        // shift delay line (fully unrolled -> stays in registers)
#pragma unroll
        for (int d = 0; d < 20; ++d) ring[d] = ring[d + 1];
        ring[20] = vnew;
    }
}

extern "C" void kernel_launch(void* const* d_in, const int* in_sizes, int n_in,
                              void* d_out, int out_size, void* d_ws, size_t ws_size,
                              hipStream_t stream) {
    const float* x = (const float*)d_in[0];
    const float* w = (const float*)d_in[1];
    float* out = (float*)d_out;
    (void)in_sizes; (void)n_in; (void)out_size; (void)d_ws; (void)ws_size;

    dim3 grid(L_ / TL, B_);   // (64, 32) = 2048 blocks
    dim3 block(F_);           // 256 threads, one per feature column
    hipLaunchKernelGGL(fan_kernel, grid, block, 0, stream, x, w, out);
}